// Round 8
// baseline (851.078 us; speedup 1.0000x reference)
//
#include <hip/hip_runtime.h>
#include <hip/hip_bf16.h>

// Problem constants (fixed by the reference)
#define NN 50000      // nodes
#define EE 800000     // raw edges
#define TE 850000     // edges + self loops
#define BK 64         // bucket capacity (P(deg>63) < 1e-13 for Poisson(17))
#define NEB 1661      // ceil((TE/2)/256) edge-pair virtual blocks
#define NGB 782       // ceil(NN/64) gemm1 virtual blocks
#define NAB 12500     // NN/4 agg virtual blocks

typedef __hip_bfloat16 bf16;
typedef __attribute__((ext_vector_type(8))) short short8v;   // 8 bf16 = 4 VGPR
typedef __attribute__((ext_vector_type(4))) float float4v;   // MFMA C/D

__device__ __forceinline__ float bu2f(unsigned short v) {
    return __uint_as_float((unsigned)v << 16);
}
__device__ __forceinline__ unsigned short f2bu(float v) {
    bf16 t = __float2bfloat16(v);
    return *(unsigned short*)&t;
}
__device__ __forceinline__ float lrelu(float e) { return (e > 0.f) ? e : 0.2f * e; }
__device__ __forceinline__ int clampn(int v) {
    return (v < 0) ? 0 : (v >= NN ? NN - 1 : v);
}

// Software grid barrier (persistent kernel; all blocks co-resident by
// __launch_bounds__(256,2) + grid = 2*CUs). Device-scope atomics +
// __threadfence for cross-XCD visibility. bar[] memset to 0 pre-launch.
__device__ __forceinline__ void gsync(int* bar, int target) {
    __syncthreads();
    if (threadIdx.x == 0) {
        __threadfence();                       // release: my writes -> device
        __hip_atomic_fetch_add(bar, 1, __ATOMIC_RELEASE, __HIP_MEMORY_SCOPE_AGENT);
        while (__hip_atomic_load(bar, __ATOMIC_ACQUIRE, __HIP_MEMORY_SCOPE_AGENT)
               < target)
            __builtin_amdgcn_s_sleep(2);
        __threadfence();                       // acquire: see others' writes
    }
    __syncthreads();
}

// ---------------- ONE persistent kernel: 5 phases, 4 software barriers ------
// ph0 zero deg | ph1 bucket CSR + weight transposes | ph2 gemm1 (MFMA)
// ph3 agg1 + fused gemm2 (out1 row via LDS, never hits HBM) | ph4 agg2+sigmoid
__global__ __launch_bounds__(256, 2) void mega_k(
    const void* __restrict__ ei, const float* __restrict__ x,
    const float* __restrict__ W1, const float* __restrict__ asr1,
    const float* __restrict__ ads1, const float* __restrict__ b1,
    const float* __restrict__ W2, const float* __restrict__ asr2,
    const float* __restrict__ ads2, const float* __restrict__ b2,
    int* __restrict__ deg, int* __restrict__ csr,
    unsigned short* __restrict__ W1T, unsigned short* __restrict__ W2T,
    unsigned short* __restrict__ P1sT, unsigned short* __restrict__ P1dT,
    unsigned short* __restrict__ P2T,
    float* __restrict__ a_src1, float* __restrict__ a_dst1,
    bf16* __restrict__ h1, bf16* __restrict__ h2,
    float* __restrict__ a_src2, float* __restrict__ a_dst2,
    int* __restrict__ bar,
    float* __restrict__ out) {
    const int tid = threadIdx.x;
    const int wv = tid >> 6, lane = tid & 63;
    const int G = gridDim.x;

    __shared__ int s_isi64;
    __shared__ int sbuf[4][64];
    __shared__ unsigned short sout[4][256];

    // int64 edge_index detection (once per block)
    if (tid < 64) {
        unsigned z = (((const unsigned*)ei)[2 * tid + 1] == 0u) ? 1u : 0u;
        unsigned long long mb = __ballot(z);
        if (tid == 0) s_isi64 = (__popcll(mb) >= 32) ? 1 : 0;
    }
    __syncthreads();
    const int isi64 = s_isi64;

    // ---- ph0: zero degree counters ----
    for (int i = blockIdx.x * 256 + tid; i < NN; i += G * 256) deg[i] = 0;
    gsync(&bar[0], G);

    // ---- ph1a: weight transposes + alpha-projection weights ----
    for (int vb = blockIdx.x; vb < 194; vb += G) {
        if (vb < 128) {
            int j = vb * 256 + tid;              // j < 32768
            int n = j >> 7, k = j & 127;
            W1T[j] = f2bu(W1[k * 256 + n]);
        } else if (vb < 192) {
            int j = (vb - 128) * 256 + tid;      // j < 16384
            int n = j >> 8, k = j & 255;
            W2T[j] = f2bu(W2[k * 64 + n]);
        } else if (vb == 192) {
            for (int j = tid; j < 2048; j += 256) {  // P1[h][k]
                int h = j >> 7, k = j & 127;
                float s = 0.f, d = 0.f;
                for (int c = 0; c < 16; ++c) {
                    float wvv = W1[k * 256 + h * 16 + c];
                    s += wvv * asr1[h * 16 + c];
                    d += wvv * ads1[h * 16 + c];
                }
                P1sT[j] = f2bu(s);
                P1dT[j] = f2bu(d);
            }
        } else {
            int k = tid;                         // P2T rows 0,1; rest zero
            float s = 0.f, d = 0.f;
            for (int c = 0; c < 64; ++c) {
                float wvv = W2[k * 64 + c];
                s += wvv * asr2[c];
                d += wvv * ads2[c];
            }
            P2T[k] = f2bu(s);
            P2T[256 + k] = f2bu(d);
            for (int j = 512 + tid; j < 4096; j += 256) P2T[j] = 0;
        }
    }
    // ---- ph1b: single-pass bucket CSR fill ----
    for (int vb = blockIdx.x; vb < NEB; vb += G) {
        int p = vb * 256 + tid;                  // pair index
        int i0 = p * 2;
        if (i0 >= TE) continue;
        int s0, d0, s1 = -1, d1 = -1;
        if (i0 + 1 < EE) {
            if (isi64) {
                longlong2 sv = ((const longlong2*)ei)[p];
                longlong2 dv = ((const longlong2*)ei)[(EE >> 1) + p];
                s0 = clampn((int)sv.x); s1 = clampn((int)sv.y);
                d0 = clampn((int)dv.x); d1 = clampn((int)dv.y);
            } else {
                int2 sv = ((const int2*)ei)[p];
                int2 dv = ((const int2*)ei)[(EE >> 1) + p];
                s0 = clampn(sv.x); s1 = clampn(sv.y);
                d0 = clampn(dv.x); d1 = clampn(dv.y);
            }
        } else {
            auto lde = [&](long long idx) {
                return clampn(isi64 ? (int)((const long long*)ei)[idx]
                                    : ((const int*)ei)[idx]);
            };
            if (i0 < EE) { s0 = lde(i0); d0 = lde((long long)EE + i0); }
            else         { s0 = i0 - EE; d0 = i0 - EE; }
            if (i0 + 1 < TE) {
                if (i0 + 1 < EE) { s1 = lde(i0 + 1); d1 = lde((long long)EE + i0 + 1); }
                else             { s1 = i0 + 1 - EE; d1 = i0 + 1 - EE; }
            }
        }
        int pos0 = atomicAdd(&deg[d0], 1);
        if (pos0 < BK) csr[d0 * BK + pos0] = s0;
        if (d1 >= 0) {
            int pos1 = atomicAdd(&deg[d1], 1);
            if (pos1 < BK) csr[d1 * BK + pos1] = s1;
        }
    }
    gsync(&bar[1], G);

    // ---- ph2: layer-1 GEMM (MFMA) + alpha projections ----
    {
        const int m = lane & 15, quad = lane >> 4;
        const float4* x4 = (const float4*)x;
        for (int vb = blockIdx.x; vb < NGB; vb += G) {
            int row0 = vb * 64 + wv * 16;
            int arow = row0 + m;
            int arowc = (arow < NN) ? arow : NN - 1;
            short8v a[4];
#pragma unroll
            for (int ks = 0; ks < 4; ++ks) {
                float4 f0 = x4[(size_t)arowc * 32 + ks * 8 + quad * 2];
                float4 f1 = x4[(size_t)arowc * 32 + ks * 8 + quad * 2 + 1];
                union { short8v v; unsigned short u[8]; } ua;
                ua.u[0] = f2bu(f0.x); ua.u[1] = f2bu(f0.y);
                ua.u[2] = f2bu(f0.z); ua.u[3] = f2bu(f0.w);
                ua.u[4] = f2bu(f1.x); ua.u[5] = f2bu(f1.y);
                ua.u[6] = f2bu(f1.z); ua.u[7] = f2bu(f1.w);
                a[ks] = ua.v;
            }
            float4v accs = {0.f, 0.f, 0.f, 0.f}, accd = {0.f, 0.f, 0.f, 0.f};
#pragma unroll
            for (int ks = 0; ks < 4; ++ks) {
                short8v bs = *(const short8v*)&P1sT[(size_t)m * 128 + quad * 8 + ks * 32];
                short8v bd = *(const short8v*)&P1dT[(size_t)m * 128 + quad * 8 + ks * 32];
                accs = __builtin_amdgcn_mfma_f32_16x16x32_bf16(a[ks], bs, accs, 0, 0, 0);
                accd = __builtin_amdgcn_mfma_f32_16x16x32_bf16(a[ks], bd, accd, 0, 0, 0);
            }
#pragma unroll
            for (int r = 0; r < 4; ++r) {
                int orow = row0 + quad * 4 + r;
                if (orow < NN) {
                    a_src1[orow * 16 + m] = accs[r];   // C col == head == m
                    a_dst1[orow * 16 + m] = accd[r];
                }
            }
            // per-tile compute+store keeps VGPR low (occupancy guarantee)
#pragma unroll
            for (int t = 0; t < 16; ++t) {
                float4v c = {0.f, 0.f, 0.f, 0.f};
                const unsigned short* wb = &W1T[(size_t)(t * 16 + m) * 128 + quad * 8];
#pragma unroll
                for (int ks = 0; ks < 4; ++ks) {
                    short8v b = *(const short8v*)&wb[ks * 32];
                    c = __builtin_amdgcn_mfma_f32_16x16x32_bf16(a[ks], b, c, 0, 0, 0);
                }
#pragma unroll
                for (int r = 0; r < 4; ++r) {
                    int orow = row0 + quad * 4 + r;
                    if (orow < NN)
                        h1[(size_t)orow * 256 + t * 16 + m] = __float2bfloat16(c[r]);
                }
            }
        }
    }
    gsync(&bar[2], G);

    // ---- ph3: layer-1 aggregation + fused layer-2 GEMM ----
    for (int vb = blockIdx.x; vb < NAB; vb += G) {
        int dst = vb * 4 + wv;
        int d = deg[dst]; if (d > BK) d = BK;
        int base = dst * BK;
        int v = (lane < d) ? csr[base + lane] : 0x7fffffff;
        int rank = 0;
        for (int j = 0; j < d; ++j) {
            int vj = __shfl(v, j, 64);
            rank += (vj < v || (vj == v && j < lane)) ? 1 : 0;
        }
        if (lane < d) sbuf[wv][rank] = v;
        if (lane < d) csr[base + lane] = sbuf[wv][lane];   // canonical order back
        int we = lane >> 4, wh = lane & 15;
        int hc = lane >> 2;
        float adst_w = a_dst1[dst * 16 + wh];
        float ax = 0.f, ay = 0.f, az = 0.f, aw = 0.f;
        float dsum = 0.f;
        int t0 = 0;
        for (; t0 + 4 <= d; t0 += 4) {
            int sr = sbuf[wv][t0 + we];
            float wr = __expf(lrelu(a_src1[sr * 16 + wh] + adst_w));
            dsum += wr;
#pragma unroll
            for (int j = 0; j < 4; ++j) {
                float wj = __shfl(wr, j * 16 + hc, 64);
                int sj = sbuf[wv][t0 + j];
                ushort4 hv = *(const ushort4*)&h1[(size_t)sj * 256 + lane * 4];
                ax += wj * bu2f(hv.x);
                ay += wj * bu2f(hv.y);
                az += wj * bu2f(hv.z);
                aw += wj * bu2f(hv.w);
            }
        }
        if (t0 < d) {
            int n = d - t0;
            float wr = 0.f;
            if (we < n) {
                int sr = sbuf[wv][t0 + we];
                wr = __expf(lrelu(a_src1[sr * 16 + wh] + adst_w));
            }
            dsum += wr;
            for (int j = 0; j < n; ++j) {
                float wj = __shfl(wr, j * 16 + hc, 64);
                int sj = sbuf[wv][t0 + j];
                ushort4 hv = *(const ushort4*)&h1[(size_t)sj * 256 + lane * 4];
                ax += wj * bu2f(hv.x);
                ay += wj * bu2f(hv.y);
                az += wj * bu2f(hv.z);
                aw += wj * bu2f(hv.w);
            }
        }
        dsum += __shfl_xor(dsum, 16, 64);
        dsum += __shfl_xor(dsum, 32, 64);
        float invd = 1.f / (__shfl(dsum, hc, 64) + 1e-16f);
        float4 bv = *(const float4*)&b1[lane * 4];
        ushort4 st;
        st.x = f2bu(ax * invd + bv.x);
        st.y = f2bu(ay * invd + bv.y);
        st.z = f2bu(az * invd + bv.z);
        st.w = f2bu(aw * invd + bv.w);
        *(ushort4*)&sout[wv][lane * 4] = st;     // out1 row stays in LDS
        __syncthreads();
        // fused gemm2: 4 rows (this block's dsts); wave wv owns col-tile wv
        {
            int mm = lane & 15, qq = lane >> 4;
            short8v a2[8];
#pragma unroll
            for (int ks = 0; ks < 8; ++ks)
                a2[ks] = *(const short8v*)&sout[mm & 3][ks * 32 + qq * 8];
            float4v c2 = {0.f, 0.f, 0.f, 0.f};
            const unsigned short* wb2 = &W2T[(size_t)(wv * 16 + mm) * 256 + qq * 8];
#pragma unroll
            for (int ks = 0; ks < 8; ++ks) {
                short8v b = *(const short8v*)&wb2[ks * 32];
                c2 = __builtin_amdgcn_mfma_f32_16x16x32_bf16(a2[ks], b, c2, 0, 0, 0);
            }
            if (qq == 0) {
#pragma unroll
                for (int r = 0; r < 4; ++r)
                    h2[(size_t)(vb * 4 + r) * 64 + wv * 16 + mm] = __float2bfloat16(c2[r]);
            }
            if (wv == 0) {       // packed alpha projections (cols 0,1 of P2T)
                float4v ca = {0.f, 0.f, 0.f, 0.f};
                const unsigned short* pb = &P2T[(size_t)mm * 256 + qq * 8];
#pragma unroll
                for (int ks = 0; ks < 8; ++ks) {
                    short8v b = *(const short8v*)&pb[ks * 32];
                    ca = __builtin_amdgcn_mfma_f32_16x16x32_bf16(a2[ks], b, ca, 0, 0, 0);
                }
                if (qq == 0 && mm == 0) {
#pragma unroll
                    for (int r = 0; r < 4; ++r) a_src2[vb * 4 + r] = ca[r];
                }
                if (qq == 0 && mm == 1) {
#pragma unroll
                    for (int r = 0; r < 4; ++r) a_dst2[vb * 4 + r] = ca[r];
                }
            }
        }
        __syncthreads();                         // protect sout reuse next iter
    }
    gsync(&bar[3], G);

    // ---- ph4: layer-2 aggregation + sigmoid ----
    for (int vb = blockIdx.x; vb < NAB; vb += G) {
        int dst = vb * 4 + wv;
        int d = deg[dst]; if (d > BK) d = BK;
        int base = dst * BK;
        float adst = a_dst2[dst];
        int half = lane >> 5, hl = lane & 31;
        float acc0 = 0.f, acc1 = 0.f, dsum = 0.f;
        float wr = 0.f; int sr = 0;
        if (lane < d) {
            sr = csr[base + lane];
            wr = __expf(lrelu(a_src2[sr] + adst));
        }
        dsum += wr;
        for (int j0 = 0; j0 < d; j0 += 8) {
            ushort2 hv[4];
            float wj[4];
#pragma unroll
            for (int u = 0; u < 4; ++u) {
                int j = j0 + u * 2 + half;       // this half's edge in the pair
                int jc = (j < d) ? j : 0;
                float w = __shfl(wr, jc, 64);
                int sj = __shfl(sr, jc, 64);
                wj[u] = (j < d) ? w : 0.f;
                hv[u] = *(const ushort2*)&h2[(size_t)sj * 64 + hl * 2];
            }
#pragma unroll
            for (int u = 0; u < 4; ++u) {
                acc0 += wj[u] * bu2f(hv[u].x);
                acc1 += wj[u] * bu2f(hv[u].y);
            }
        }
        acc0 += __shfl_xor(acc0, 32, 64);
        acc1 += __shfl_xor(acc1, 32, 64);
#pragma unroll
        for (int o = 32; o >= 1; o >>= 1) dsum += __shfl_xor(dsum, o, 64);
        if (half == 0) {
            float inv = 1.f / (dsum + 1e-16f);
            float o0 = acc0 * inv + b2[hl * 2];
            float o1 = acc1 * inv + b2[hl * 2 + 1];
            float2 stv;
            stv.x = 1.f / (1.f + __expf(-o0));
            stv.y = 1.f / (1.f + __expf(-o1));
            *(float2*)&out[(size_t)dst * 64 + hl * 2] = stv;
        }
    }
}

// ---------------- host ------------------------------------------------------

extern "C" void kernel_launch(void* const* d_in, const int* in_sizes, int n_in,
                              void* d_out, int out_size, void* d_ws, size_t ws_size,
                              hipStream_t stream) {
    const float* x    = (const float*)d_in[0];
    const void*  ei   = d_in[1];
    const float* W1   = (const float*)d_in[2];
    const float* asr1 = (const float*)d_in[3];
    const float* ads1 = (const float*)d_in[4];
    const float* b1   = (const float*)d_in[5];
    const float* W2   = (const float*)d_in[6];
    const float* asr2 = (const float*)d_in[7];
    const float* ads2 = (const float*)d_in[8];
    const float* b2   = (const float*)d_in[9];
    float* out = (float*)d_out;

    char* w = (char*)d_ws;
    auto carve = [&](size_t bytes) {
        void* p = (void*)w;
        w += (bytes + 255) & ~(size_t)255;
        return p;
    };
    int*    csr      = (int*)carve((size_t)NN * BK * 4);       // 12.8 MB buckets
    int*    deg      = (int*)carve((size_t)NN * 4);
    float*  a_src1   = (float*)carve((size_t)NN * 16 * 4);     // 3.2 MB
    float*  a_dst1   = (float*)carve((size_t)NN * 16 * 4);     // 3.2 MB
    unsigned short* W1T  = (unsigned short*)carve(128 * 256 * 2);  // 64 KB
    unsigned short* W2T  = (unsigned short*)carve(256 * 64 * 2);   // 32 KB
    unsigned short* P1sT = (unsigned short*)carve(16 * 128 * 2);   // 4 KB
    unsigned short* P1dT = (unsigned short*)carve(16 * 128 * 2);   // 4 KB
    unsigned short* P2T  = (unsigned short*)carve(16 * 256 * 2);   // 8 KB
    bf16*   h1       = (bf16*)carve((size_t)NN * 256 * 2);     // 25.6 MB
    bf16*   h2       = (bf16*)carve((size_t)NN * 64 * 2);      // 6.4 MB (no alias: ph3 reads h1 while writing h2)
    float*  a_src2   = (float*)carve((size_t)NN * 4);
    float*  a_dst2   = (float*)carve((size_t)NN * 4);
    int*    bar      = (int*)carve(4 * sizeof(int));

    // grid sizing: co-resident by __launch_bounds__(256,2) -> 2 blocks/CU
    static int gblocks = 0;
    if (gblocks == 0) {
        int ncu = 256;
        hipDeviceProp_t prop;
        int dev = 0;
        if (hipGetDevice(&dev) == hipSuccess &&
            hipGetDeviceProperties(&prop, dev) == hipSuccess &&
            prop.multiProcessorCount > 0)
            ncu = prop.multiProcessorCount;
        gblocks = 2 * ncu;                     // 512 on MI355X
        if (gblocks > NAB) gblocks = NAB;
        if (gblocks < 1) gblocks = 256;
    }

    hipMemsetAsync(bar, 0, 4 * sizeof(int), stream);
    mega_k<<<gblocks, 256, 0, stream>>>(
        ei, x, W1, asr1, ads1, b1, W2, asr2, ads2, b2,
        deg, csr, W1T, W2T, P1sT, P1dT, P2T,
        a_src1, a_dst1, h1, h2, a_src2, a_dst2, bar, out);
}

// Round 9
// 301.957 us; speedup vs baseline: 2.8185x; 2.8185x over previous
//
#include <hip/hip_runtime.h>
#include <hip/hip_bf16.h>

// Problem constants (fixed by the reference)
#define NN 50000      // nodes
#define EE 800000     // raw edges
#define TE 850000     // edges + self loops
#define BK 64         // bucket capacity (P(deg>63) < 1e-13 for Poisson(17))

typedef __hip_bfloat16 bf16;
typedef __attribute__((ext_vector_type(8))) short short8v;   // 8 bf16 = 4 VGPR
typedef __attribute__((ext_vector_type(4))) float float4v;   // MFMA C/D

__device__ __forceinline__ float bu2f(unsigned short v) {
    return __uint_as_float((unsigned)v << 16);
}
__device__ __forceinline__ unsigned short f2bu(float v) {
    bf16 t = __float2bfloat16(v);
    return *(unsigned short*)&t;
}
__device__ __forceinline__ float lrelu(float e) { return (e > 0.f) ? e : 0.2f * e; }
__device__ __forceinline__ int clampn(int v) {
    return (v < 0) ? 0 : (v >= NN ? NN - 1 : v);
}

// Per-block int64 detection: first 64 odd words of edge_index all zero iff int64.
__device__ __forceinline__ int block_isi64(const void* ei) {
    __shared__ int sflag;
    int t = threadIdx.x;
    if (t < 64) {
        unsigned z = (((const unsigned*)ei)[2 * t + 1] == 0u) ? 1u : 0u;
        unsigned long long m = __ballot(z);
        if (t == 0) sflag = (__popcll(m) >= 32) ? 1 : 0;
    }
    __syncthreads();
    return sflag;
}

// ---------------- ONE-pass CSR bucket fill + weight transposes + projections -
// blocks 0..127: W1T. 128..191: W2T. 192: P1sT/P1dT. 193: P2T.
__global__ void prep_k(const void* __restrict__ ei, int* __restrict__ deg,
                       int* __restrict__ csr,
                       const float* __restrict__ W1, const float* __restrict__ W2,
                       const float* __restrict__ asr1, const float* __restrict__ ads1,
                       const float* __restrict__ asr2, const float* __restrict__ ads2,
                       unsigned short* __restrict__ W1T,
                       unsigned short* __restrict__ W2T,
                       unsigned short* __restrict__ P1sT,
                       unsigned short* __restrict__ P1dT,
                       unsigned short* __restrict__ P2T) {
    int isi64 = block_isi64(ei);
    int b = blockIdx.x, t = threadIdx.x;
    if (b < 128) {
        int j = b * 256 + t;                 // j < 32768
        int n = j >> 7, k = j & 127;
        W1T[j] = f2bu(W1[k * 256 + n]);
    } else if (b < 192) {
        int j = (b - 128) * 256 + t;         // j < 16384
        int n = j >> 8, k = j & 255;
        W2T[j] = f2bu(W2[k * 64 + n]);
    } else if (b == 192) {
        for (int j = t; j < 2048; j += 256) {   // P1[h][k], h=j>>7, k=j&127
            int h = j >> 7, k = j & 127;
            float s = 0.f, d = 0.f;
            for (int c = 0; c < 16; ++c) {
                float wv = W1[k * 256 + h * 16 + c];
                s += wv * asr1[h * 16 + c];
                d += wv * ads1[h * 16 + c];
            }
            P1sT[j] = f2bu(s);
            P1dT[j] = f2bu(d);
        }
    } else if (b == 193) {
        // P2T[0][k]=proj_src, P2T[1][k]=proj_dst, rows 2..15 zero (16x256)
        int k = t;
        float s = 0.f, d = 0.f;
        for (int c = 0; c < 64; ++c) {
            float wv = W2[k * 64 + c];
            s += wv * asr2[c];
            d += wv * ads2[c];
        }
        P2T[k] = f2bu(s);
        P2T[256 + k] = f2bu(d);
        for (int j = 512 + t; j < 4096; j += 256) P2T[j] = 0;
    }
    int p = b * 256 + t;                     // pair index
    int i0 = p * 2;
    if (i0 >= TE) return;
    int s0, d0, s1 = -1, d1 = -1;
    if (i0 + 1 < EE) {
        if (isi64) {
            longlong2 sv = ((const longlong2*)ei)[p];
            longlong2 dv = ((const longlong2*)ei)[(EE >> 1) + p];
            s0 = clampn((int)sv.x); s1 = clampn((int)sv.y);
            d0 = clampn((int)dv.x); d1 = clampn((int)dv.y);
        } else {
            int2 sv = ((const int2*)ei)[p];
            int2 dv = ((const int2*)ei)[(EE >> 1) + p];
            s0 = clampn(sv.x); s1 = clampn(sv.y);
            d0 = clampn(dv.x); d1 = clampn(dv.y);
        }
    } else {
        auto lde = [&](long long idx) {
            return clampn(isi64 ? (int)((const long long*)ei)[idx] : ((const int*)ei)[idx]);
        };
        if (i0 < EE) { s0 = lde(i0); d0 = lde((long long)EE + i0); }
        else         { s0 = i0 - EE; d0 = i0 - EE; }
        if (i0 + 1 < TE) {
            if (i0 + 1 < EE) { s1 = lde(i0 + 1); d1 = lde((long long)EE + i0 + 1); }
            else             { s1 = i0 + 1 - EE; d1 = i0 + 1 - EE; }
        }
    }
    int pos0 = atomicAdd(&deg[d0], 1);
    if (pos0 < BK) csr[d0 * BK + pos0] = s0;
    if (d1 >= 0) {
        int pos1 = atomicAdd(&deg[d1], 1);
        if (pos1 < BK) csr[d1 * BK + pos1] = s1;
    }
}

// ---------------- Layer 1 GEMM on MFMA; alphas via projection MFMAs ---------
__global__ __launch_bounds__(256) void gemm1_k(
    const float* __restrict__ x, const unsigned short* __restrict__ W1T,
    const unsigned short* __restrict__ P1sT, const unsigned short* __restrict__ P1dT,
    bf16* __restrict__ h1, float* __restrict__ a_src, float* __restrict__ a_dst) {
    int wv = threadIdx.x >> 6, lane = threadIdx.x & 63;
    int m = lane & 15, quad = lane >> 4;
    int row0 = blockIdx.x * 64 + wv * 16;
    int arow = row0 + m;
    int arowc = (arow < NN) ? arow : NN - 1;
    const float4* x4 = (const float4*)x;
    short8v a[4];
#pragma unroll
    for (int ks = 0; ks < 4; ++ks) {
        float4 f0 = x4[(size_t)arowc * 32 + ks * 8 + quad * 2];
        float4 f1 = x4[(size_t)arowc * 32 + ks * 8 + quad * 2 + 1];
        union { short8v v; unsigned short u[8]; } ua;
        ua.u[0] = f2bu(f0.x); ua.u[1] = f2bu(f0.y);
        ua.u[2] = f2bu(f0.z); ua.u[3] = f2bu(f0.w);
        ua.u[4] = f2bu(f1.x); ua.u[5] = f2bu(f1.y);
        ua.u[6] = f2bu(f1.z); ua.u[7] = f2bu(f1.w);
        a[ks] = ua.v;
    }
    float4v accs = {0.f, 0.f, 0.f, 0.f}, accd = {0.f, 0.f, 0.f, 0.f};
#pragma unroll
    for (int ks = 0; ks < 4; ++ks) {
        short8v bs = *(const short8v*)&P1sT[(size_t)m * 128 + quad * 8 + ks * 32];
        short8v bd = *(const short8v*)&P1dT[(size_t)m * 128 + quad * 8 + ks * 32];
        accs = __builtin_amdgcn_mfma_f32_16x16x32_bf16(a[ks], bs, accs, 0, 0, 0);
        accd = __builtin_amdgcn_mfma_f32_16x16x32_bf16(a[ks], bd, accd, 0, 0, 0);
    }
    float4v acc[16];
#pragma unroll
    for (int t = 0; t < 16; ++t) {
        float4v c = {0.f, 0.f, 0.f, 0.f};
        const unsigned short* wb = &W1T[(size_t)(t * 16 + m) * 128 + quad * 8];
#pragma unroll
        for (int ks = 0; ks < 4; ++ks) {
            short8v b = *(const short8v*)&wb[ks * 32];
            c = __builtin_amdgcn_mfma_f32_16x16x32_bf16(a[ks], b, c, 0, 0, 0);
        }
        acc[t] = c;
    }
#pragma unroll
    for (int t = 0; t < 16; ++t) {
#pragma unroll
        for (int r = 0; r < 4; ++r) {
            int orow = row0 + quad * 4 + r;
            if (orow < NN)
                h1[(size_t)orow * 256 + t * 16 + m] = __float2bfloat16(acc[t][r]);
        }
    }
#pragma unroll
    for (int r = 0; r < 4; ++r) {
        int orow = row0 + quad * 4 + r;
        if (orow < NN) {
            a_src[orow * 16 + m] = accs[r];   // C col == head == m
            a_dst[orow * 16 + m] = accd[r];
        }
    }
}

// ---------------- Layer 1 aggregation + FUSED layer-2 GEMM ------------------
// Round-6 agg1 (wave-per-dst, in-wave bucket sort) but the out1 row never
// touches HBM: it goes to LDS and the block's 4 waves immediately MFMA it
// against W2T (wave wv owns col-tile wv); wave 0 adds the packed P2T alpha
// projections. Validated in mega_k round 8 (absmax identical); here it runs
// at full occupancy. sout padded to 272 (544B row): gemm2 fragment reads are
// 2-way banked (free) instead of 4-way.
__global__ __launch_bounds__(256) void agg1f_k(
    const int* __restrict__ deg, int* __restrict__ csr,
    const float* __restrict__ a_src, const float* __restrict__ a_dst,
    const bf16* __restrict__ h1, const float* __restrict__ b1,
    const unsigned short* __restrict__ W2T, const unsigned short* __restrict__ P2T,
    bf16* __restrict__ h2, float* __restrict__ a_src2, float* __restrict__ a_dst2) {
    __shared__ int sbuf[4][64];
    __shared__ unsigned short sout[4][272];
    int wv = threadIdx.x >> 6, lane = threadIdx.x & 63;
    int dst = blockIdx.x * 4 + wv;          // grid = NN/4 exactly
    int d = deg[dst]; if (d > BK) d = BK;
    int base = dst * BK;
    int v = (lane < d) ? csr[base + lane] : 0x7fffffff;
    int rank = 0;
    for (int j = 0; j < d; ++j) {
        int vj = __shfl(v, j, 64);
        rank += (vj < v || (vj == v && j < lane)) ? 1 : 0;
    }
    if (lane < d) sbuf[wv][rank] = v;
    if (lane < d) csr[base + lane] = sbuf[wv][lane];   // canonical order back
    int we = lane >> 4, wh = lane & 15;
    int hc = lane >> 2;
    float adst_w = a_dst[dst * 16 + wh];
    float ax = 0.f, ay = 0.f, az = 0.f, aw = 0.f;
    float dsum = 0.f;
    int t0 = 0;
    for (; t0 + 4 <= d; t0 += 4) {
        int sr = sbuf[wv][t0 + we];
        float wr = __expf(lrelu(a_src[sr * 16 + wh] + adst_w));
        dsum += wr;
#pragma unroll
        for (int j = 0; j < 4; ++j) {
            float wj = __shfl(wr, j * 16 + hc, 64);
            int sj = sbuf[wv][t0 + j];
            ushort4 hv = *(const ushort4*)&h1[(size_t)sj * 256 + lane * 4];
            ax += wj * bu2f(hv.x);
            ay += wj * bu2f(hv.y);
            az += wj * bu2f(hv.z);
            aw += wj * bu2f(hv.w);
        }
    }
    if (t0 < d) {
        int n = d - t0;
        float wr = 0.f;
        if (we < n) {
            int sr = sbuf[wv][t0 + we];
            wr = __expf(lrelu(a_src[sr * 16 + wh] + adst_w));
        }
        dsum += wr;
        for (int j = 0; j < n; ++j) {
            float wj = __shfl(wr, j * 16 + hc, 64);
            int sj = sbuf[wv][t0 + j];
            ushort4 hv = *(const ushort4*)&h1[(size_t)sj * 256 + lane * 4];
            ax += wj * bu2f(hv.x);
            ay += wj * bu2f(hv.y);
            az += wj * bu2f(hv.z);
            aw += wj * bu2f(hv.w);
        }
    }
    dsum += __shfl_xor(dsum, 16, 64);
    dsum += __shfl_xor(dsum, 32, 64);
    float invd = 1.f / (__shfl(dsum, hc, 64) + 1e-16f);
    float4 bv = *(const float4*)&b1[lane * 4];
    ushort4 st;
    st.x = f2bu(ax * invd + bv.x);
    st.y = f2bu(ay * invd + bv.y);
    st.z = f2bu(az * invd + bv.z);
    st.w = f2bu(aw * invd + bv.w);
    *(ushort4*)&sout[wv][lane * 4] = st;     // out1 row stays in LDS
    __syncthreads();
    // fused gemm2: 4 rows (this block's dsts); wave wv owns col-tile wv
    {
        int mm = lane & 15, qq = lane >> 4;
        short8v a2[8];
#pragma unroll
        for (int ks = 0; ks < 8; ++ks)
            a2[ks] = *(const short8v*)&sout[mm & 3][ks * 32 + qq * 8];
        float4v c2 = {0.f, 0.f, 0.f, 0.f};
        const unsigned short* wb2 = &W2T[(size_t)(wv * 16 + mm) * 256 + qq * 8];
#pragma unroll
        for (int ks = 0; ks < 8; ++ks) {
            short8v b = *(const short8v*)&wb2[ks * 32];
            c2 = __builtin_amdgcn_mfma_f32_16x16x32_bf16(a2[ks], b, c2, 0, 0, 0);
        }
        if (qq == 0) {
#pragma unroll
            for (int r = 0; r < 4; ++r)
                h2[(size_t)(blockIdx.x * 4 + r) * 64 + wv * 16 + mm] =
                    __float2bfloat16(c2[r]);
        }
        if (wv == 0) {           // packed alpha projections (cols 0,1 of P2T)
            float4v ca = {0.f, 0.f, 0.f, 0.f};
            const unsigned short* pb = &P2T[(size_t)mm * 256 + qq * 8];
#pragma unroll
            for (int ks = 0; ks < 8; ++ks) {
                short8v b = *(const short8v*)&pb[ks * 32];
                ca = __builtin_amdgcn_mfma_f32_16x16x32_bf16(a2[ks], b, ca, 0, 0, 0);
            }
            if (qq == 0 && mm == 0) {
#pragma unroll
                for (int r = 0; r < 4; ++r) a_src2[blockIdx.x * 4 + r] = ca[r];
            }
            if (qq == 0 && mm == 1) {
#pragma unroll
                for (int r = 0; r < 4; ++r) a_dst2[blockIdx.x * 4 + r] = ca[r];
            }
        }
    }
}

// ---------------- Layer 2 aggregation + sigmoid (f32 out) -------------------
// Half-wave per edge, ushort2 loads, 4 edge-pairs unrolled; d <= 64 (buckets).
__global__ __launch_bounds__(256) void agg2_k(
    const int* __restrict__ deg, const int* __restrict__ csr,
    const float* __restrict__ a_src2, const float* __restrict__ a_dst2,
    const bf16* __restrict__ h2, const float* __restrict__ b2,
    float* __restrict__ out) {
    int wv = threadIdx.x >> 6;
    int lane = threadIdx.x & 63;
    int dst = blockIdx.x * 4 + wv;
    if (dst >= NN) return;
    int d = deg[dst]; if (d > BK) d = BK;
    int base = dst * BK;
    float adst = a_dst2[dst];
    int half = lane >> 5, hl = lane & 31;
    float acc0 = 0.f, acc1 = 0.f, dsum = 0.f;
    float wr = 0.f; int sr = 0;
    if (lane < d) {
        sr = csr[base + lane];
        wr = __expf(lrelu(a_src2[sr] + adst));
    }
    dsum += wr;
    for (int j0 = 0; j0 < d; j0 += 8) {
        ushort2 hv[4];
        float wj[4];
#pragma unroll
        for (int u = 0; u < 4; ++u) {
            int j = j0 + u * 2 + half;      // this half's edge in the pair
            int jc = (j < d) ? j : 0;
            float w = __shfl(wr, jc, 64);
            int sj = __shfl(sr, jc, 64);
            wj[u] = (j < d) ? w : 0.f;
            hv[u] = *(const ushort2*)&h2[(size_t)sj * 64 + hl * 2];
        }
#pragma unroll
        for (int u = 0; u < 4; ++u) {
            acc0 += wj[u] * bu2f(hv[u].x);
            acc1 += wj[u] * bu2f(hv[u].y);
        }
    }
    // lane L and L+32 hold the same 2 channels over disjoint edge subsets
    acc0 += __shfl_xor(acc0, 32, 64);
    acc1 += __shfl_xor(acc1, 32, 64);
#pragma unroll
    for (int o = 32; o >= 1; o >>= 1) dsum += __shfl_xor(dsum, o, 64);
    if (half == 0) {
        float inv = 1.f / (dsum + 1e-16f);
        float o0 = acc0 * inv + b2[hl * 2];
        float o1 = acc1 * inv + b2[hl * 2 + 1];
        float2 st;
        st.x = 1.f / (1.f + __expf(-o0));
        st.y = 1.f / (1.f + __expf(-o1));
        *(float2*)&out[(size_t)dst * 64 + hl * 2] = st;
    }
}

// ---------------- host ------------------------------------------------------

extern "C" void kernel_launch(void* const* d_in, const int* in_sizes, int n_in,
                              void* d_out, int out_size, void* d_ws, size_t ws_size,
                              hipStream_t stream) {
    const float* x    = (const float*)d_in[0];
    const void*  ei   = d_in[1];
    const float* W1   = (const float*)d_in[2];
    const float* asr1 = (const float*)d_in[3];
    const float* ads1 = (const float*)d_in[4];
    const float* b1   = (const float*)d_in[5];
    const float* W2   = (const float*)d_in[6];
    const float* asr2 = (const float*)d_in[7];
    const float* ads2 = (const float*)d_in[8];
    const float* b2   = (const float*)d_in[9];
    float* out = (float*)d_out;

    char* w = (char*)d_ws;
    auto carve = [&](size_t bytes) {
        void* p = (void*)w;
        w += (bytes + 255) & ~(size_t)255;
        return p;
    };
    int*    csr      = (int*)carve((size_t)NN * BK * 4);       // 12.8 MB buckets
    int*    deg      = (int*)carve((size_t)NN * 4);
    float*  a_src1   = (float*)carve((size_t)NN * 16 * 4);     // 3.2 MB
    float*  a_dst1   = (float*)carve((size_t)NN * 16 * 4);     // 3.2 MB
    unsigned short* W1T  = (unsigned short*)carve(128 * 256 * 2);  // 64 KB
    unsigned short* W2T  = (unsigned short*)carve(256 * 64 * 2);   // 32 KB
    unsigned short* P1sT = (unsigned short*)carve(16 * 128 * 2);   // 4 KB
    unsigned short* P1dT = (unsigned short*)carve(16 * 128 * 2);   // 4 KB
    unsigned short* P2T  = (unsigned short*)carve(16 * 256 * 2);   // 8 KB
    bf16*   h1       = (bf16*)carve((size_t)NN * 256 * 2);     // 25.6 MB
    bf16*   h2       = (bf16*)carve((size_t)NN * 64 * 2);      // 6.4 MB (no alias: agg1f reads h1 while writing h2)
    float*  a_src2   = (float*)carve((size_t)NN * 4);
    float*  a_dst2   = (float*)carve((size_t)NN * 4);

    hipMemsetAsync(deg, 0, (size_t)NN * 4, stream);

    const int pgrid = ((TE + 1) / 2 + 255) / 256;
    prep_k<<<pgrid, 256, 0, stream>>>(ei, deg, csr, W1, W2, asr1, ads1, asr2, ads2,
                                      W1T, W2T, P1sT, P1dT, P2T);
    gemm1_k<<<(NN + 63) / 64, 256, 0, stream>>>(x, W1T, P1sT, P1dT, h1, a_src1, a_dst1);
    agg1f_k<<<NN / 4, 256, 0, stream>>>(deg, csr, a_src1, a_dst1, h1, b1,
                                        W2T, P2T, h2, a_src2, a_dst2);
    agg2_k<<<(NN + 3) / 4, 256, 0, stream>>>(deg, csr, a_src2, a_dst2, h2, b2, out);
}

// Round 10
// 270.882 us; speedup vs baseline: 3.1419x; 1.1147x over previous
//
#include <hip/hip_runtime.h>
#include <hip/hip_bf16.h>

// Problem constants (fixed by the reference)
#define NN 50000      // nodes
#define EE 800000     // raw edges
#define TE 850000     // edges + self loops
#define BK 64         // bucket capacity (P(deg>63) < 1e-13 for Poisson(17))
#define NGB 782       // ceil(NN/64) gemm1 virtual blocks
#define NEB 1661      // ceil((TE/2)/256) edge-pair virtual blocks

typedef __hip_bfloat16 bf16;
typedef __attribute__((ext_vector_type(8))) short short8v;   // 8 bf16 = 4 VGPR
typedef __attribute__((ext_vector_type(4))) float float4v;   // MFMA C/D

__device__ __forceinline__ float bu2f(unsigned short v) {
    return __uint_as_float((unsigned)v << 16);
}
__device__ __forceinline__ unsigned short f2bu(float v) {
    bf16 t = __float2bfloat16(v);
    return *(unsigned short*)&t;
}
__device__ __forceinline__ float lrelu(float e) { return (e > 0.f) ? e : 0.2f * e; }
__device__ __forceinline__ int clampn(int v) {
    return (v < 0) ? 0 : (v >= NN ? NN - 1 : v);
}

// ---------------- weight transposes + projections + deg zero ----------------
// blocks 0..127: W1T. 128..191: W2T. 192: P1sT/P1dT. 193: P2T. All: zero deg.
__global__ __launch_bounds__(256) void wprep_k(
    const float* __restrict__ W1, const float* __restrict__ W2,
    const float* __restrict__ asr1, const float* __restrict__ ads1,
    const float* __restrict__ asr2, const float* __restrict__ ads2,
    unsigned short* __restrict__ W1T, unsigned short* __restrict__ W2T,
    unsigned short* __restrict__ P1sT, unsigned short* __restrict__ P1dT,
    unsigned short* __restrict__ P2T, int* __restrict__ deg) {
    int b = blockIdx.x, t = threadIdx.x;
    for (int i = b * 256 + t; i < NN; i += 256 * 256) deg[i] = 0;
    if (b < 128) {
        int j = b * 256 + t;                 // j < 32768
        int n = j >> 7, k = j & 127;
        W1T[j] = f2bu(W1[k * 256 + n]);
    } else if (b < 192) {
        int j = (b - 128) * 256 + t;         // j < 16384
        int n = j >> 8, k = j & 255;
        W2T[j] = f2bu(W2[k * 64 + n]);
    } else if (b == 192) {
        for (int j = t; j < 2048; j += 256) {   // P1[h][k], h=j>>7, k=j&127
            int h = j >> 7, k = j & 127;
            float s = 0.f, d = 0.f;
            for (int c = 0; c < 16; ++c) {
                float wv = W1[k * 256 + h * 16 + c];
                s += wv * asr1[h * 16 + c];
                d += wv * ads1[h * 16 + c];
            }
            P1sT[j] = f2bu(s);
            P1dT[j] = f2bu(d);
        }
    } else if (b == 193) {
        // P2T[0][k]=proj_src, P2T[1][k]=proj_dst, rows 2..15 zero (16x256)
        int k = t;
        float s = 0.f, d = 0.f;
        for (int c = 0; c < 64; ++c) {
            float wv = W2[k * 64 + c];
            s += wv * asr2[c];
            d += wv * ads2[c];
        }
        P2T[k] = f2bu(s);
        P2T[256 + k] = f2bu(d);
        for (int j = 512 + t; j < 4096; j += 256) P2T[j] = 0;
    }
}

// ---------------- fused: gemm1 (blocks < NGB) || edge bucket pass (rest) ----
// The two families are data-independent (gemm1 needs only W1T/P1 from wprep_k;
// edge pass needs only ei+deg) -> MFMA-heavy and memory/atomic-heavy blocks
// co-schedule on the CUs, hiding the edge pass under gemm1.
__global__ __launch_bounds__(256) void eg1_k(
    const void* __restrict__ ei, const float* __restrict__ x,
    const unsigned short* __restrict__ W1T,
    const unsigned short* __restrict__ P1sT, const unsigned short* __restrict__ P1dT,
    int* __restrict__ deg, int* __restrict__ csr,
    bf16* __restrict__ h1, float* __restrict__ a_src, float* __restrict__ a_dst) {
    if (blockIdx.x < NGB) {
        // ---- gemm1 path (verbatim round-6 gemm1_k) ----
        int wv = threadIdx.x >> 6, lane = threadIdx.x & 63;
        int m = lane & 15, quad = lane >> 4;
        int row0 = blockIdx.x * 64 + wv * 16;
        int arow = row0 + m;
        int arowc = (arow < NN) ? arow : NN - 1;
        const float4* x4 = (const float4*)x;
        short8v a[4];
#pragma unroll
        for (int ks = 0; ks < 4; ++ks) {
            float4 f0 = x4[(size_t)arowc * 32 + ks * 8 + quad * 2];
            float4 f1 = x4[(size_t)arowc * 32 + ks * 8 + quad * 2 + 1];
            union { short8v v; unsigned short u[8]; } ua;
            ua.u[0] = f2bu(f0.x); ua.u[1] = f2bu(f0.y);
            ua.u[2] = f2bu(f0.z); ua.u[3] = f2bu(f0.w);
            ua.u[4] = f2bu(f1.x); ua.u[5] = f2bu(f1.y);
            ua.u[6] = f2bu(f1.z); ua.u[7] = f2bu(f1.w);
            a[ks] = ua.v;
        }
        float4v accs = {0.f, 0.f, 0.f, 0.f}, accd = {0.f, 0.f, 0.f, 0.f};
#pragma unroll
        for (int ks = 0; ks < 4; ++ks) {
            short8v bs = *(const short8v*)&P1sT[(size_t)m * 128 + quad * 8 + ks * 32];
            short8v bd = *(const short8v*)&P1dT[(size_t)m * 128 + quad * 8 + ks * 32];
            accs = __builtin_amdgcn_mfma_f32_16x16x32_bf16(a[ks], bs, accs, 0, 0, 0);
            accd = __builtin_amdgcn_mfma_f32_16x16x32_bf16(a[ks], bd, accd, 0, 0, 0);
        }
        float4v acc[16];
#pragma unroll
        for (int t = 0; t < 16; ++t) {
            float4v c = {0.f, 0.f, 0.f, 0.f};
            const unsigned short* wb = &W1T[(size_t)(t * 16 + m) * 128 + quad * 8];
#pragma unroll
            for (int ks = 0; ks < 4; ++ks) {
                short8v b = *(const short8v*)&wb[ks * 32];
                c = __builtin_amdgcn_mfma_f32_16x16x32_bf16(a[ks], b, c, 0, 0, 0);
            }
            acc[t] = c;
        }
#pragma unroll
        for (int t = 0; t < 16; ++t) {
#pragma unroll
            for (int r = 0; r < 4; ++r) {
                int orow = row0 + quad * 4 + r;
                if (orow < NN)
                    h1[(size_t)orow * 256 + t * 16 + m] = __float2bfloat16(acc[t][r]);
            }
        }
#pragma unroll
        for (int r = 0; r < 4; ++r) {
            int orow = row0 + quad * 4 + r;
            if (orow < NN) {
                a_src[orow * 16 + m] = accs[r];   // C col == head == m
                a_dst[orow * 16 + m] = accd[r];
            }
        }
        return;
    }
    // ---- edge bucket pass (verbatim round-6 prep_k edge part) ----
    __shared__ int sflag;
    int t = threadIdx.x;
    if (t < 64) {
        unsigned z = (((const unsigned*)ei)[2 * t + 1] == 0u) ? 1u : 0u;
        unsigned long long mb = __ballot(z);
        if (t == 0) sflag = (__popcll(mb) >= 32) ? 1 : 0;
    }
    __syncthreads();
    int isi64 = sflag;
    int p = (blockIdx.x - NGB) * 256 + t;    // pair index
    int i0 = p * 2;
    if (i0 >= TE) return;
    int s0, d0, s1 = -1, d1 = -1;
    if (i0 + 1 < EE) {
        if (isi64) {
            longlong2 sv = ((const longlong2*)ei)[p];
            longlong2 dv = ((const longlong2*)ei)[(EE >> 1) + p];
            s0 = clampn((int)sv.x); s1 = clampn((int)sv.y);
            d0 = clampn((int)dv.x); d1 = clampn((int)dv.y);
        } else {
            int2 sv = ((const int2*)ei)[p];
            int2 dv = ((const int2*)ei)[(EE >> 1) + p];
            s0 = clampn(sv.x); s1 = clampn(sv.y);
            d0 = clampn(dv.x); d1 = clampn(dv.y);
        }
    } else {
        auto lde = [&](long long idx) {
            return clampn(isi64 ? (int)((const long long*)ei)[idx] : ((const int*)ei)[idx]);
        };
        if (i0 < EE) { s0 = lde(i0); d0 = lde((long long)EE + i0); }
        else         { s0 = i0 - EE; d0 = i0 - EE; }
        if (i0 + 1 < TE) {
            if (i0 + 1 < EE) { s1 = lde(i0 + 1); d1 = lde((long long)EE + i0 + 1); }
            else             { s1 = i0 + 1 - EE; d1 = i0 + 1 - EE; }
        }
    }
    int pos0 = atomicAdd(&deg[d0], 1);
    if (pos0 < BK) csr[d0 * BK + pos0] = s0;
    if (d1 >= 0) {
        int pos1 = atomicAdd(&deg[d1], 1);
        if (pos1 < BK) csr[d1 * BK + pos1] = s1;
    }
}

// ---------------- Layer 1 aggregation: wave-per-dst, in-wave bucket sort ----
__global__ __launch_bounds__(256) void agg1_k(
    const int* __restrict__ deg, int* __restrict__ csr,
    const float* __restrict__ a_src, const float* __restrict__ a_dst,
    const bf16* __restrict__ h1, const float* __restrict__ b1,
    bf16* __restrict__ out1) {
    __shared__ int sbuf[4][64];
    int wv = threadIdx.x >> 6, lane = threadIdx.x & 63;
    int dst = blockIdx.x * 4 + wv;          // grid = NN/4 exactly
    int d = deg[dst]; if (d > BK) d = BK;
    int base = dst * BK;
    int v = (lane < d) ? csr[base + lane] : 0x7fffffff;
    int rank = 0;
    for (int j = 0; j < d; ++j) {
        int vj = __shfl(v, j, 64);
        rank += (vj < v || (vj == v && j < lane)) ? 1 : 0;
    }
    if (lane < d) sbuf[wv][rank] = v;
    if (lane < d) csr[base + lane] = sbuf[wv][lane];   // canonical order back
    int we = lane >> 4, wh = lane & 15;
    int hc = lane >> 2;
    float adst_w = a_dst[dst * 16 + wh];
    float ax = 0.f, ay = 0.f, az = 0.f, aw = 0.f;
    float dsum = 0.f;
    int t0 = 0;
    for (; t0 + 4 <= d; t0 += 4) {
        int sr = sbuf[wv][t0 + we];
        float wr = __expf(lrelu(a_src[sr * 16 + wh] + adst_w));
        dsum += wr;
#pragma unroll
        for (int j = 0; j < 4; ++j) {
            float wj = __shfl(wr, j * 16 + hc, 64);
            int sj = sbuf[wv][t0 + j];
            ushort4 hv = *(const ushort4*)&h1[(size_t)sj * 256 + lane * 4];
            ax += wj * bu2f(hv.x);
            ay += wj * bu2f(hv.y);
            az += wj * bu2f(hv.z);
            aw += wj * bu2f(hv.w);
        }
    }
    if (t0 < d) {
        int n = d - t0;
        float wr = 0.f;
        if (we < n) {
            int sr = sbuf[wv][t0 + we];
            wr = __expf(lrelu(a_src[sr * 16 + wh] + adst_w));
        }
        dsum += wr;
        for (int j = 0; j < n; ++j) {
            float wj = __shfl(wr, j * 16 + hc, 64);
            int sj = sbuf[wv][t0 + j];
            ushort4 hv = *(const ushort4*)&h1[(size_t)sj * 256 + lane * 4];
            ax += wj * bu2f(hv.x);
            ay += wj * bu2f(hv.y);
            az += wj * bu2f(hv.z);
            aw += wj * bu2f(hv.w);
        }
    }
    dsum += __shfl_xor(dsum, 16, 64);
    dsum += __shfl_xor(dsum, 32, 64);
    float invd = 1.f / (__shfl(dsum, hc, 64) + 1e-16f);
    float4 bv = *(const float4*)&b1[lane * 4];
    ushort4 st;
    st.x = f2bu(ax * invd + bv.x);
    st.y = f2bu(ay * invd + bv.y);
    st.z = f2bu(az * invd + bv.z);
    st.w = f2bu(aw * invd + bv.w);
    *(ushort4*)&out1[(size_t)dst * 256 + lane * 4] = st;
}

// ---------------- Layer 2 GEMM on MFMA; alphas via packed projection --------
__global__ __launch_bounds__(256) void gemm2_k(
    const bf16* __restrict__ out1, const unsigned short* __restrict__ W2T,
    const unsigned short* __restrict__ P2T,
    bf16* __restrict__ h2, float* __restrict__ a_src2, float* __restrict__ a_dst2) {
    int wv = threadIdx.x >> 6, lane = threadIdx.x & 63;
    int m = lane & 15, quad = lane >> 4;
    int row0 = blockIdx.x * 64 + wv * 16;
    int arow = row0 + m;
    int arowc = (arow < NN) ? arow : NN - 1;
    const unsigned short* ab = (const unsigned short*)out1;
    short8v a[8];
#pragma unroll
    for (int ks = 0; ks < 8; ++ks)
        a[ks] = *(const short8v*)&ab[(size_t)arowc * 256 + ks * 32 + quad * 8];
    float4v acca = {0.f, 0.f, 0.f, 0.f};
#pragma unroll
    for (int ks = 0; ks < 8; ++ks) {
        short8v b = *(const short8v*)&P2T[(size_t)m * 256 + quad * 8 + ks * 32];
        acca = __builtin_amdgcn_mfma_f32_16x16x32_bf16(a[ks], b, acca, 0, 0, 0);
    }
    float4v acc[4];
#pragma unroll
    for (int t = 0; t < 4; ++t) {
        float4v c = {0.f, 0.f, 0.f, 0.f};
        const unsigned short* wb = &W2T[(size_t)(t * 16 + m) * 256 + quad * 8];
#pragma unroll
        for (int ks = 0; ks < 8; ++ks) {
            short8v b = *(const short8v*)&wb[ks * 32];
            c = __builtin_amdgcn_mfma_f32_16x16x32_bf16(a[ks], b, c, 0, 0, 0);
        }
        acc[t] = c;
    }
#pragma unroll
    for (int t = 0; t < 4; ++t) {
#pragma unroll
        for (int r = 0; r < 4; ++r) {
            int orow = row0 + quad * 4 + r;
            if (orow < NN)
                h2[(size_t)orow * 64 + t * 16 + m] = __float2bfloat16(acc[t][r]);
        }
    }
#pragma unroll
    for (int r = 0; r < 4; ++r) {
        int orow = row0 + quad * 4 + r;
        if (orow < NN) {
            if (m == 0) a_src2[orow] = acca[r];   // col 0 = src projection
            if (m == 1) a_dst2[orow] = acca[r];   // col 1 = dst projection
        }
    }
}

// ---------------- Layer 2 aggregation + sigmoid (f32 out) -------------------
__global__ __launch_bounds__(256) void agg2_k(
    const int* __restrict__ deg, const int* __restrict__ csr,
    const float* __restrict__ a_src2, const float* __restrict__ a_dst2,
    const bf16* __restrict__ h2, const float* __restrict__ b2,
    float* __restrict__ out) {
    int wv = threadIdx.x >> 6;
    int lane = threadIdx.x & 63;
    int dst = blockIdx.x * 4 + wv;
    if (dst >= NN) return;
    int d = deg[dst]; if (d > BK) d = BK;
    int base = dst * BK;
    float adst = a_dst2[dst];
    int half = lane >> 5, hl = lane & 31;
    float acc0 = 0.f, acc1 = 0.f, dsum = 0.f;
    float wr = 0.f; int sr = 0;
    if (lane < d) {
        sr = csr[base + lane];
        wr = __expf(lrelu(a_src2[sr] + adst));
    }
    dsum += wr;
    for (int j0 = 0; j0 < d; j0 += 8) {
        ushort2 hv[4];
        float wj[4];
#pragma unroll
        for (int u = 0; u < 4; ++u) {
            int j = j0 + u * 2 + half;      // this half's edge in the pair
            int jc = (j < d) ? j : 0;
            float w = __shfl(wr, jc, 64);
            int sj = __shfl(sr, jc, 64);
            wj[u] = (j < d) ? w : 0.f;
            hv[u] = *(const ushort2*)&h2[(size_t)sj * 64 + hl * 2];
        }
#pragma unroll
        for (int u = 0; u < 4; ++u) {
            acc0 += wj[u] * bu2f(hv[u].x);
            acc1 += wj[u] * bu2f(hv[u].y);
        }
    }
    // lane L and L+32 hold the same 2 channels over disjoint edge subsets
    acc0 += __shfl_xor(acc0, 32, 64);
    acc1 += __shfl_xor(acc1, 32, 64);
#pragma unroll
    for (int o = 32; o >= 1; o >>= 1) dsum += __shfl_xor(dsum, o, 64);
    if (half == 0) {
        float inv = 1.f / (dsum + 1e-16f);
        float o0 = acc0 * inv + b2[hl * 2];
        float o1 = acc1 * inv + b2[hl * 2 + 1];
        float2 st;
        st.x = 1.f / (1.f + __expf(-o0));
        st.y = 1.f / (1.f + __expf(-o1));
        *(float2*)&out[(size_t)dst * 64 + hl * 2] = st;
    }
}

// ---------------- host ------------------------------------------------------

extern "C" void kernel_launch(void* const* d_in, const int* in_sizes, int n_in,
                              void* d_out, int out_size, void* d_ws, size_t ws_size,
                              hipStream_t stream) {
    const float* x    = (const float*)d_in[0];
    const void*  ei   = d_in[1];
    const float* W1   = (const float*)d_in[2];
    const float* asr1 = (const float*)d_in[3];
    const float* ads1 = (const float*)d_in[4];
    const float* b1   = (const float*)d_in[5];
    const float* W2   = (const float*)d_in[6];
    const float* asr2 = (const float*)d_in[7];
    const float* ads2 = (const float*)d_in[8];
    const float* b2   = (const float*)d_in[9];
    float* out = (float*)d_out;

    char* w = (char*)d_ws;
    auto carve = [&](size_t bytes) {
        void* p = (void*)w;
        w += (bytes + 255) & ~(size_t)255;
        return p;
    };
    int*    csr      = (int*)carve((size_t)NN * BK * 4);       // 12.8 MB buckets
    int*    deg      = (int*)carve((size_t)NN * 4);
    float*  a_src1   = (float*)carve((size_t)NN * 16 * 4);     // 3.2 MB
    float*  a_dst1   = (float*)carve((size_t)NN * 16 * 4);     // 3.2 MB
    unsigned short* W1T  = (unsigned short*)carve(128 * 256 * 2);  // 64 KB
    unsigned short* W2T  = (unsigned short*)carve(256 * 64 * 2);   // 32 KB
    unsigned short* P1sT = (unsigned short*)carve(16 * 128 * 2);   // 4 KB
    unsigned short* P1dT = (unsigned short*)carve(16 * 128 * 2);   // 4 KB
    unsigned short* P2T  = (unsigned short*)carve(16 * 256 * 2);   // 8 KB
    bf16*   h1       = (bf16*)carve((size_t)NN * 256 * 2);     // 25.6 MB
    bf16*   out1     = (bf16*)carve((size_t)NN * 256 * 2);     // 25.6 MB
    // layer-2 buffers alias h1 (dead after agg1)
    char*   l2base   = (char*)h1;
    bf16*   h2       = (bf16*)l2base;
    float*  a_src2   = (float*)(l2base + (size_t)NN * 64 * 2);
    float*  a_dst2   = a_src2 + NN;

    wprep_k<<<256, 256, 0, stream>>>(W1, W2, asr1, ads1, asr2, ads2,
                                     W1T, W2T, P1sT, P1dT, P2T, deg);
    eg1_k<<<NGB + NEB, 256, 0, stream>>>(ei, x, W1T, P1sT, P1dT,
                                         deg, csr, h1, a_src1, a_dst1);
    agg1_k<<<NN / 4, 256, 0, stream>>>(deg, csr, a_src1, a_dst1, h1, b1, out1);
    gemm2_k<<<(NN + 63) / 64, 256, 0, stream>>>(out1, W2T, P2T, h2, a_src2, a_dst2);
    agg2_k<<<(NN + 3) / 4, 256, 0, stream>>>(deg, csr, a_src2, a_dst2, h2, b2, out);
}